// Round 3
// baseline (224.507 us; speedup 1.0000x reference)
//
#include <hip/hip_runtime.h>

// DifferentiableRankIntegration: B=1024, tau=0.1, K=60.
// rank_pos[c,j] = 1 + sum_k sig((s_ck-s_cj)/tau)*neg[c,k]
// rank_neg[c,j] = 1 + sum_k sig((s_ck-s_cj)/tau)*pos[c,k]
// out = 61*(w_v/(60+rank_v) + w_l/(60+rank_l))
//
// R18 == R17 resubmit (R17 hit "MI355X container failed twice" infra
// error; kernel never ran). BISECTION BUILD. R15/R16 (banded+corrections)
// fail at absmax ~3.1e-2 INSENSITIVE to band margin and nrcp accuracy =>
// structural bug suspected in the sort/band/correction machinery, not the
// core math. This version removes ALL of it: exact full-window TREE over
// all 1024 k, original j-order in LDS. Surviving surface under test:
// exp2 staging, TREE/nrcp octet math, Phase B (positives), epilogue.
//  - analytic worst error ~3e-2 RANK units (SCL leakage on clamped far-
//    below terms) -> ~5e-4 output error, 40x under the 2e-2 threshold.
//  - est. ~110-150us (2.1G sigmoids @ ~3 VALU each) — correctness first;
//    perf to be recovered by re-adding banding once verified.

#define NB 1024
#define CEXP 14.426950408889634f  /* log2(e)/tau, tau=0.1 */
#define SCL  0.000030517578125f   /* 2^-15 */
#define NJOB 32                   /* 8 j-chunks x 2 k-halves x 2 matrices */
#define MAXPOS 64

__device__ __forceinline__ float fma_sat(float a, float b, float c) {
    float d;  // VOP3 clamp [0,1]
    asm("v_fma_f32 %0, %1, %2, %3 clamp" : "=v"(d) : "v"(a), "v"(b), "v"(c));
    return d;
}

__device__ __forceinline__ float nrcp(float d) {
    // d in [2^-120, 1]; magic seed + 2 Newton -> ~1.4e-6 rel (undershoot).
    float r = __uint_as_float(0x7EF311C3u - __float_as_uint(d));
    r = r * fmaf(-d, r, 2.0f);
    r = r * fmaf(-d, r, 2.0f);
    return r;
}

// sum_{i=1..8} 1/y_i, y_i = clamp(Es*R_i + SCL) in [2^-15, 1]
#define TREE(Es, ra, rb, A)                                      \
    {                                                            \
        const float y1 = fma_sat((Es), (ra).x, SCL);             \
        const float y2 = fma_sat((Es), (ra).y, SCL);             \
        const float y3 = fma_sat((Es), (ra).z, SCL);             \
        const float y4 = fma_sat((Es), (ra).w, SCL);             \
        const float y5 = fma_sat((Es), (rb).x, SCL);             \
        const float y6 = fma_sat((Es), (rb).y, SCL);             \
        const float y7 = fma_sat((Es), (rb).z, SCL);             \
        const float y8 = fma_sat((Es), (rb).w, SCL);             \
        const float p12 = y1 * y2, p34 = y3 * y4;                \
        const float p56 = y5 * y6, p78 = y7 * y8;                \
        const float s12 = y1 + y2, s34 = y3 + y4;                \
        const float s56 = y5 + y6, s78 = y7 + y8;                \
        const float q1 = p12 * p34, q2 = p56 * p78;              \
        const float n1 = fmaf(s12, p34, s34 * p12);              \
        const float n2 = fmaf(s56, p78, s78 * p56);              \
        const float num = fmaf(n1, q2, n2 * q1);                 \
        const float den = q1 * q2;                               \
        (A) = fmaf(num, nrcp(den), (A));                         \
    }

__global__ __launch_bounds__(512) void drank_kernel(
    const float* __restrict__ s_v, const float* __restrict__ s_l,
    const unsigned char* __restrict__ pos_m,
    const unsigned char* __restrict__ neg_m,
    const float* __restrict__ w_v, const float* __restrict__ w_l,
    float* __restrict__ out)
{
    __shared__ float  listRv[NB], listRl[NB];     // R in ORIGINAL j order
    __shared__ float  sAv1[NB], sAl1[NB];         // k-half partials
    __shared__ float  sAv2[NB], sAl2[NB];
    __shared__ float2 posR[MAXPOS];
    __shared__ int    npos_s, jobCtr;

    const int c = blockIdx.x;
    const int t = threadIdx.x;
    const long row = (long)c * NB;

    if (t == 0) { npos_s = 0; jobCtr = 0; }
    __syncthreads();

    // Mask dtype detect from element (0,0): diagonal -> pos=1, neg=0.
    const unsigned int W =
        ((const unsigned int*)pos_m)[0] ^ ((const unsigned int*)neg_m)[0];
    const int mode = (W == 0x01010101u) ? 0 : ((W == 0x3f800000u) ? 2 : 1);

    // ---- Staging: thread t owns original j/k-pair 2t..2t+1 ----
    const int j0 = t * 2;
    const float2 sjv = *(const float2*)(s_v + row + j0);
    const float2 sjl = *(const float2*)(s_l + row + j0);
    const float svu[2] = {sjv.x, sjv.y};
    const float slu[2] = {sjl.x, sjl.y};

    float Rv[2], Rl[2], Ev[2], El[2];
    #pragma unroll
    for (int u = 0; u < 2; ++u) {
        Rv[u] = __builtin_amdgcn_exp2f(-svu[u] * CEXP);
        Rl[u] = __builtin_amdgcn_exp2f(-slu[u] * CEXP);
        Ev[u] = __builtin_amdgcn_exp2f(svu[u] * CEXP);
        El[u] = __builtin_amdgcn_exp2f(slu[u] * CEXP);
    }
    *(float2*)(listRv + j0) = make_float2(Rv[0], Rv[1]);
    *(float2*)(listRl + j0) = make_float2(Rl[0], Rl[1]);

    bool pj[2];
    if (mode == 0) {
        const unsigned short b = ((const unsigned short*)pos_m)[(row >> 1) + t];
        pj[0] = (b & 0x00ffu) != 0; pj[1] = (b & 0xff00u) != 0;
    } else if (mode == 2) {
        const float2 p = *(const float2*)((const float*)pos_m + row + j0);
        pj[0] = p.x != 0.f; pj[1] = p.y != 0.f;
    } else {
        const int2 p = *(const int2*)((const int*)pos_m + row + j0);
        pj[0] = p.x != 0; pj[1] = p.y != 0;
    }
    #pragma unroll
    for (int u = 0; u < 2; ++u) {
        if (pj[u]) {
            const int idx = atomicAdd(&npos_s, 1);
            if (idx < MAXPOS) posR[idx] = make_float2(Rv[u], Rl[u]);
        }
    }
    __syncthreads();

    // ---- Exact eval: 32 jobs = 8 j-chunks x 2 k-halves x 2 matrices ----
    const int lane = t & 63;

    for (;;) {
        int jid0 = 0;
        if (lane == 0) jid0 = atomicAdd(&jobCtr, 1);
        const int jid = __builtin_amdgcn_readfirstlane(jid0);
        if (jid >= NJOB) break;
        const int ch = jid >> 2;          // j-chunk 0..7
        const int m  = (jid >> 1) & 1;    // 0 v, 1 l
        const int h  = jid & 1;           // k-half

        const float*  LR = m ? listRl : listRv;
        float*        SA = h ? (m ? sAl2 : sAv2) : (m ? sAl1 : sAv1);
        const float4* L4 = (const float4*)LR;

        const int p0 = ch * 128 + 2 * lane;          // original j, j+1
        const float2 R2 = *(const float2*)(LR + p0);
        const float EsX = SCL * __builtin_amdgcn_rcpf(R2.x);
        const float EsY = SCL * __builtin_amdgcn_rcpf(R2.y);

        float a0 = 0.f, a1 = 0.f;
        const int klo = h * 512, khi = klo + 512;
        #pragma unroll 2
        for (int p = klo; p < khi; p += 8) {
            const float4 ra = L4[p >> 2];
            const float4 rb = L4[(p >> 2) + 1];
            TREE(EsX, ra, rb, a0);
            TREE(EsY, ra, rb, a1);
        }
        float2 r;
        r.x = a0 * SCL;
        r.y = a1 * SCL;
        *(float2*)(SA + p0) = r;
    }

    // ---- Phase B (before final barrier: overlaps other waves' jobs) ----
    float sPv[2] = {0.f, 0.f};
    float sPl[2] = {0.f, 0.f};
    const int np = min(npos_s, MAXPOS);
    for (int i = 0; i < np; ++i) {
        const float2 rp = posR[i];
        #pragma unroll
        for (int u = 0; u < 2; ++u) {
            sPv[u] += __builtin_amdgcn_rcpf(fmaf(Ev[u], rp.x, 1.0f));
            sPl[u] += __builtin_amdgcn_rcpf(fmaf(El[u], rp.y, 1.0f));
        }
    }
    __syncthreads();

    // ---- Epilogue (original j order; sum the two k-half partials) ----
    const float2 av1 = *(const float2*)(sAv1 + j0);
    const float2 av2 = *(const float2*)(sAv2 + j0);
    const float2 al1 = *(const float2*)(sAl1 + j0);
    const float2 al2 = *(const float2*)(sAl2 + j0);
    const float sAvu[2] = {av1.x + av2.x, av1.y + av2.y};
    const float sAlu[2] = {al1.x + al2.x, al1.y + al2.y};
    const float2 wv = *(const float2*)(w_v + row + j0);
    const float2 wl = *(const float2*)(w_l + row + j0);
    const float wva[2] = {wv.x, wv.y};
    const float wla[2] = {wl.x, wl.y};
    float o[2];
    #pragma unroll
    for (int u = 0; u < 2; ++u) {
        const float rv = pj[u] ? (1.0f + sAvu[u] - sPv[u]) : (1.0f + sPv[u]);
        const float rl = pj[u] ? (1.0f + sAlu[u] - sPl[u]) : (1.0f + sPl[u]);
        o[u] = 61.0f * (wva[u] / (60.0f + rv) + wla[u] / (60.0f + rl));
    }
    float2 o2;
    o2.x = o[0]; o2.y = o[1];
    *(float2*)(out + row + j0) = o2;
}

extern "C" void kernel_launch(void* const* d_in, const int* in_sizes, int n_in,
                              void* d_out, int out_size, void* d_ws, size_t ws_size,
                              hipStream_t stream) {
    const float* s_v = (const float*)d_in[0];
    const float* s_l = (const float*)d_in[1];
    const unsigned char* pos_m = (const unsigned char*)d_in[2];
    const unsigned char* neg_m = (const unsigned char*)d_in[3];
    const float* w_v = (const float*)d_in[4];
    const float* w_l = (const float*)d_in[5];
    float* out = (float*)d_out;

    drank_kernel<<<dim3(NB), dim3(512), 0, stream>>>(s_v, s_l, pos_m, neg_m, w_v, w_l, out);
}

// Round 5
// 139.622 us; speedup vs baseline: 1.6080x; 1.6080x over previous
//
#include <hip/hip_runtime.h>

// DifferentiableRankIntegration: B=1024, tau=0.1, K=60.
// rank_pos[c,j] = 1 + sum_k sig((s_ck-s_cj)/tau)*neg[c,k]
// rank_neg[c,j] = 1 + sum_k sig((s_ck-s_cj)/tau)*pos[c,k]
// out = 61*(w_v/(60+rank_v) + w_l/(60+rank_l))
//
// R21 — FRESH BANDED REWRITE. Bisection: R17 (exact, orig order) PASSES;
// R19 (sort machinery, corrections provably inert) FAILS at 3.125e-2 =>
// bug in {scatter, scan phase, jj-writes}. This build keeps verified code
// (staging, TREE, nrcp, Phase B, epilogue) and re-engineers the suspects:
//  - dedicated cursor arrays (NO aliasing of sAv1 — removes type-punned
//    LDS atomic suspicion)
//  - jobs write LANE-OWNED sorted-position slots (R17's verified write
//    pattern); epilogue gathers via inverse permutation inv[j]
//  - bucket of each sorted pos in bkt[] (uchar), no listJ
//  - margin DBUK=6 (0.336 score): trunc err e^{-10.1}*1024 ~ 0.04 ranks
//  - scans: clamp only before squaring (1st-order sums exact); band-edge
//    evaluation keeps extreme-E/R products finite (audit in session log)
// Budget: ~0.09 ranks worst -> ~1.5e-3 output; bf16 floor 3.9e-3 dominates.
// Predicted ~75-95us dispatch (TREE pairs / ~2.9 vs R17's 178us).

#define NB 1024
#define CEXP 14.426950408889634f  /* log2(e)/tau, tau=0.1 */
#define SCL  0.000030517578125f   /* 2^-15 */
#define NBUK 128
#define BUK0 4.3f                 /* bucket range [-4.3,4.3] */
#define BUKW 14.883720930f        /* 128/8.6 -> width 0.0672 */
#define DBUK 6                    /* band margin >= 5*0.0672 = 0.336 */
#define CHSZ 128
#define NJOB 32                   /* 8 chunks x 2 matrices x 2 halves */
#define MAXPOS 64
#define ECLMP 1e17f

__device__ __forceinline__ float fma_sat(float a, float b, float c) {
    float d;  // VOP3 clamp [0,1]
    asm("v_fma_f32 %0, %1, %2, %3 clamp" : "=v"(d) : "v"(a), "v"(b), "v"(c));
    return d;
}

__device__ __forceinline__ float nrcp(float d) {
    // d in [2^-120, 1]; magic seed + 2 Newton -> ~1.4e-6 rel (undershoot).
    float r = __uint_as_float(0x7EF311C3u - __float_as_uint(d));
    r = r * fmaf(-d, r, 2.0f);
    r = r * fmaf(-d, r, 2.0f);
    return r;
}

// sum_{i=1..8} 1/y_i, y_i = clamp(Es*R_i + SCL) in [2^-15, 1]
#define TREE(Es, ra, rb, A)                                      \
    {                                                            \
        const float y1 = fma_sat((Es), (ra).x, SCL);             \
        const float y2 = fma_sat((Es), (ra).y, SCL);             \
        const float y3 = fma_sat((Es), (ra).z, SCL);             \
        const float y4 = fma_sat((Es), (ra).w, SCL);             \
        const float y5 = fma_sat((Es), (rb).x, SCL);             \
        const float y6 = fma_sat((Es), (rb).y, SCL);             \
        const float y7 = fma_sat((Es), (rb).z, SCL);             \
        const float y8 = fma_sat((Es), (rb).w, SCL);             \
        const float p12 = y1 * y2, p34 = y3 * y4;                \
        const float p56 = y5 * y6, p78 = y7 * y8;                \
        const float s12 = y1 + y2, s34 = y3 + y4;                \
        const float s56 = y5 + y6, s78 = y7 + y8;                \
        const float q1 = p12 * p34, q2 = p56 * p78;              \
        const float n1 = fmaf(s12, p34, s34 * p12);              \
        const float n2 = fmaf(s56, p78, s78 * p56);              \
        const float num = fmaf(n1, q2, n2 * q1);                 \
        const float den = q1 * q2;                               \
        (A) = fmaf(num, nrcp(den), (A));                         \
    }

__global__ __launch_bounds__(512) void drank_kernel(
    const float* __restrict__ s_v, const float* __restrict__ s_l,
    const unsigned char* __restrict__ pos_m,
    const unsigned char* __restrict__ neg_m,
    const float* __restrict__ w_v, const float* __restrict__ w_l,
    float* __restrict__ out)
{
    __shared__ float  listRv[NB], listRl[NB];     // R, bucket-sorted order
    __shared__ unsigned char bktv[NB], bktl[NB];  // bucket of sorted pos
    __shared__ int    invv[NB], invl[NB];         // orig j -> sorted pos
    __shared__ float  sAv1[NB], sAv2[NB];         // half-band partials
    __shared__ float  sAl1[NB], sAl2[NB];         //   (sorted-pos indexed)
    __shared__ int    offv[NBUK + 1], offl[NBUK + 1];
    __shared__ int    curv[NBUK], curl[NBUK];     // DEDICATED cursors
    __shared__ float  SRv[129], SEv[129];         // octet scans: R-suffix,
    __shared__ float  SR2v[129], SE2v[129];       //   E-prefix, 2nd order
    __shared__ float  SRl[129], SEl[129];
    __shared__ float  SR2l[129], SE2l[129];
    __shared__ float2 posR[MAXPOS];
    __shared__ int    npos_s, jobCtr;

    const int c = blockIdx.x;
    const int t = threadIdx.x;
    const long row = (long)c * NB;

    if (t < NBUK) { curv[t] = 0; curl[t] = 0; }
    if (t == 0) { npos_s = 0; jobCtr = 0; }
    __syncthreads();

    // Mask dtype detect from element (0,0): diagonal -> pos=1, neg=0.
    const unsigned int W =
        ((const unsigned int*)pos_m)[0] ^ ((const unsigned int*)neg_m)[0];
    const int mode = (W == 0x01010101u) ? 0 : ((W == 0x3f800000u) ? 2 : 1);

    // ---- Staging: thread t owns original j/k-pair 2t..2t+1 ----
    const int j0 = t * 2;
    const float2 sjv = *(const float2*)(s_v + row + j0);
    const float2 sjl = *(const float2*)(s_l + row + j0);
    const float svu[2] = {sjv.x, sjv.y};
    const float slu[2] = {sjl.x, sjl.y};

    float Rv[2], Rl[2], Ev[2], El[2];
    int ibv[2], ibl[2];
    #pragma unroll
    for (int u = 0; u < 2; ++u) {
        Rv[u] = __builtin_amdgcn_exp2f(-svu[u] * CEXP);
        Rl[u] = __builtin_amdgcn_exp2f(-slu[u] * CEXP);
        Ev[u] = __builtin_amdgcn_exp2f(svu[u] * CEXP);
        El[u] = __builtin_amdgcn_exp2f(slu[u] * CEXP);
        ibv[u] = max(0, min(NBUK - 1, (int)((svu[u] + BUK0) * BUKW)));
        ibl[u] = max(0, min(NBUK - 1, (int)((slu[u] + BUK0) * BUKW)));
        atomicAdd(&curv[ibv[u]], 1);
        atomicAdd(&curl[ibl[u]], 1);
    }

    bool pj[2];
    if (mode == 0) {
        const unsigned short b = ((const unsigned short*)pos_m)[(row >> 1) + t];
        pj[0] = (b & 0x00ffu) != 0; pj[1] = (b & 0xff00u) != 0;
    } else if (mode == 2) {
        const float2 p = *(const float2*)((const float*)pos_m + row + j0);
        pj[0] = p.x != 0.f; pj[1] = p.y != 0.f;
    } else {
        const int2 p = *(const int2*)((const int*)pos_m + row + j0);
        pj[0] = p.x != 0; pj[1] = p.y != 0;
    }
    #pragma unroll
    for (int u = 0; u < 2; ++u) {
        if (pj[u]) {
            const int idx = atomicAdd(&npos_s, 1);
            if (idx < MAXPOS) posR[idx] = make_float2(Rv[u], Rl[u]);
        }
    }
    __syncthreads();

    // ---- Bucket prefix-sums: wave shuffle-scan (2 waves, 2 buckets/lane);
    //      writes off[] and scatter cursors ----
    if (t < 128) {
        const int m = t >> 6, l = t & 63;
        int* cnt = m ? curl : curv;
        int* off = m ? offl : offv;
        const int c0 = cnt[2 * l], c1 = cnt[2 * l + 1];
        int s = c0 + c1;
        #pragma unroll
        for (int d = 1; d < 64; d <<= 1) {
            const int y = __shfl_up(s, d, 64);
            if (l >= d) s += y;
        }
        const int excl = s - c0 - c1;
        off[2 * l] = excl;     off[2 * l + 1] = excl + c0;
        cnt[2 * l] = excl;     cnt[2 * l + 1] = excl + c0;
        if (l == 63) off[NBUK] = s;
    }
    __syncthreads();

    // ---- Scatter: R + bucket into sorted lists; record inverse perm ----
    #pragma unroll
    for (int u = 0; u < 2; ++u) {
        const int pv = atomicAdd(&curv[ibv[u]], 1);
        listRv[pv] = Rv[u];
        bktv[pv]   = (unsigned char)ibv[u];
        invv[j0 + u] = pv;
        const int pl = atomicAdd(&curl[ibl[u]], 1);
        listRl[pl] = Rl[u];
        bktl[pl]   = (unsigned char)ibl[u];
        invl[j0 + u] = pl;
    }
    __syncthreads();

    // ---- Fused octet sums + shuffle scans: 8 waves, one flavor each.
    //      wid: 0 SRv(suf) 1 SEv(pre) 2 SRl(suf) 3 SEl(pre)
    //           4 SR2v(suf) 5 SE2v(pre) 6 SR2l(suf) 7 SE2l(pre)
    //      NOTE: clamp applied ONLY before squaring (1st-order exact) ----
    {
        const int wid = t >> 6, l = t & 63;
        const int m   = (wid >> 1) & 1;   // 0 v, 1 l
        const int fE  = wid & 1;          // E flavor (prefix) vs R (suffix)
        const int sq  = wid >> 2;         // squared
        const float4* L4 = (const float4*)(m ? listRl : listRv);
        float* arr;
        switch (wid) {
            case 0: arr = SRv;  break;  case 1: arr = SEv;  break;
            case 2: arr = SRl;  break;  case 3: arr = SEl;  break;
            case 4: arr = SR2v; break;  case 5: arr = SE2v; break;
            case 6: arr = SR2l; break;  default: arr = SE2l; break;
        }
        const int o0 = fE ? (2 * l) : (127 - 2 * l);
        const int o1 = fE ? (2 * l + 1) : (126 - 2 * l);
        float s01[2];
        #pragma unroll
        for (int q = 0; q < 2; ++q) {
            const int o = q ? o1 : o0;
            const float4 a = L4[2 * o], b = L4[2 * o + 1];
            float x[8] = {a.x, a.y, a.z, a.w, b.x, b.y, b.z, b.w};
            float acc = 0.f;
            #pragma unroll
            for (int i = 0; i < 8; ++i) {
                const float v = fE ? __builtin_amdgcn_rcpf(x[i]) : x[i];
                if (sq) { const float vc = fminf(v, ECLMP); acc += vc * vc; }
                else    { acc += v; }
            }
            s01[q] = acc;
        }
        float s = s01[0] + s01[1];
        #pragma unroll
        for (int d = 1; d < 64; d <<= 1) {
            const float y = __shfl_up(s, d, 64);
            if (l >= d) s += y;
        }
        if (fE) {   // exclusive prefix: arr[o] = sum over octets < o
            const float excl = s - s01[0] - s01[1];
            arr[o0] = excl;  arr[o1] = excl + s01[0];
            if (l == 63) arr[128] = s;
        } else {    // suffix: arr[o] = sum over octets >= o
            arr[o1] = s;  arr[o0] = s - s01[1];
            if (l == 0) arr[128] = 0.f;
        }
    }
    __syncthreads();

    // ---- Banded eval: 32 LPT jobs = 8 chunks x 2 matrices x 2 halves.
    //      Jobs write LANE-OWNED sorted-position slots (no scatter). ----
    static const unsigned char CORD[8] = {3, 4, 2, 5, 1, 6, 0, 7};
    const int lane = t & 63;

    for (;;) {
        int jid0 = 0;
        if (lane == 0) jid0 = atomicAdd(&jobCtr, 1);
        const int jid = __builtin_amdgcn_readfirstlane(jid0);
        if (jid >= NJOB) break;
        const int ch = CORD[jid >> 2];
        const int m  = (jid >> 1) & 1;
        const int h  = jid & 1;

        const float* LR  = m ? listRl : listRv;
        const unsigned char* BK = m ? bktl : bktv;
        const int*   off = m ? offl : offv;
        float*       SA  = h ? (m ? sAl2 : sAv2) : (m ? sAl1 : sAv1);
        const float* SR  = m ? SRl : SRv;
        const float* SE  = m ? SEl : SEv;
        const float* SR2 = m ? SR2l : SR2v;
        const float* SE2 = m ? SE2l : SE2v;
        const float4* L4 = (const float4*)LR;

        const int p0 = ch * CHSZ + 2 * lane;             // sorted positions
        const float2 R2 = *(const float2*)(LR + p0);
        const float Ex = __builtin_amdgcn_rcpf(R2.x);    // E = 1/R
        const float Ey = __builtin_amdgcn_rcpf(R2.y);
        const float EsX = SCL * Ex;
        const float EsY = SCL * Ey;

        const int bs = (int)BK[ch * CHSZ];               // min bucket (sorted)
        const int be = (int)BK[ch * CHSZ + CHSZ - 1];    // max bucket
        const int lo0 = off[max(0, bs - DBUK)] & ~7;
        const int hi0 = (off[min(NBUK - 1, be + DBUK) + 1] + 7) & ~7;
        const int mid = ((lo0 + hi0) >> 1) & ~7;         // octet-aligned
        const int lo = h ? mid : lo0;
        const int hi = h ? hi0 : mid;

        float a0 = 0.f, a1 = 0.f;
        #pragma unroll 2
        for (int p = lo; p < hi; p += 8) {
            const float4 ra = L4[p >> 2];
            const float4 rb = L4[(p >> 2) + 1];
            TREE(EsX, ra, rb, a0);
            TREE(EsY, ra, rb, a1);
        }
        // tail corrections (2nd order):
        //  above (h=1): cnt - E_j*sumR + min(E_j)^2*sum(minR)^2
        //  below (h=0): R_j*sumE - min(R_j)^2*sum(minE)^2
        //  1st-order factors unclamped (products bounded by construction);
        //  clamps only on squared factors (overflow guard, understates by
        //  <= true tail term for the rare |s|>3.91 elements).
        float cx, cy;
        if (h) {
            const float sr = SR[hi0 >> 3], sr2 = SR2[hi0 >> 3];
            const float Exc = fminf(Ex, ECLMP), Eyc = fminf(Ey, ECLMP);
            cx = fmaf(Exc * Exc, sr2, (float)(NB - hi0) - Ex * sr);
            cy = fmaf(Eyc * Eyc, sr2, (float)(NB - hi0) - Ey * sr);
        } else {
            const float se = SE[lo0 >> 3], se2 = SE2[lo0 >> 3];
            const float Rxc = fminf(R2.x, ECLMP), Ryc = fminf(R2.y, ECLMP);
            cx = fmaf(-(Rxc * Rxc), se2, R2.x * se);
            cy = fmaf(-(Ryc * Ryc), se2, R2.y * se);
        }
        float2 r;
        r.x = fmaf(a0, SCL, cx);
        r.y = fmaf(a1, SCL, cy);
        *(float2*)(SA + p0) = r;     // lane-owned contiguous write
    }

    // ---- Phase B (before final barrier: overlaps other waves' jobs) ----
    float sPv[2] = {0.f, 0.f};
    float sPl[2] = {0.f, 0.f};
    const int np = min(npos_s, MAXPOS);
    for (int i = 0; i < np; ++i) {
        const float2 rp = posR[i];
        #pragma unroll
        for (int u = 0; u < 2; ++u) {
            sPv[u] += __builtin_amdgcn_rcpf(fmaf(Ev[u], rp.x, 1.0f));
            sPl[u] += __builtin_amdgcn_rcpf(fmaf(El[u], rp.y, 1.0f));
        }
    }
    __syncthreads();

    // ---- Epilogue: gather via inverse permutation, original j order ----
    const int iv0 = invv[j0], iv1 = invv[j0 + 1];
    const int il0 = invl[j0], il1 = invl[j0 + 1];
    const float sAvu[2] = {sAv1[iv0] + sAv2[iv0], sAv1[iv1] + sAv2[iv1]};
    const float sAlu[2] = {sAl1[il0] + sAl2[il0], sAl1[il1] + sAl2[il1]};
    const float2 wv = *(const float2*)(w_v + row + j0);
    const float2 wl = *(const float2*)(w_l + row + j0);
    const float wva[2] = {wv.x, wv.y};
    const float wla[2] = {wl.x, wl.y};
    float o[2];
    #pragma unroll
    for (int u = 0; u < 2; ++u) {
        const float rv = pj[u] ? (1.0f + sAvu[u] - sPv[u]) : (1.0f + sPv[u]);
        const float rl = pj[u] ? (1.0f + sAlu[u] - sPl[u]) : (1.0f + sPl[u]);
        o[u] = 61.0f * (wva[u] / (60.0f + rv) + wla[u] / (60.0f + rl));
    }
    float2 o2;
    o2.x = o[0]; o2.y = o[1];
    *(float2*)(out + row + j0) = o2;
}

extern "C" void kernel_launch(void* const* d_in, const int* in_sizes, int n_in,
                              void* d_out, int out_size, void* d_ws, size_t ws_size,
                              hipStream_t stream) {
    const float* s_v = (const float*)d_in[0];
    const float* s_l = (const float*)d_in[1];
    const unsigned char* pos_m = (const unsigned char*)d_in[2];
    const unsigned char* neg_m = (const unsigned char*)d_in[3];
    const float* w_v = (const float*)d_in[4];
    const float* w_l = (const float*)d_in[5];
    float* out = (float*)d_out;

    drank_kernel<<<dim3(NB), dim3(512), 0, stream>>>(s_v, s_l, pos_m, neg_m, w_v, w_l, out);
}

// Round 6
// 127.137 us; speedup vs baseline: 1.7659x; 1.0982x over previous
//
#include <hip/hip_runtime.h>

// DifferentiableRankIntegration: B=1024, tau=0.1, K=60.
// rank_pos[c,j] = 1 + sum_k sig((s_ck-s_cj)/tau)*neg[c,k]
// rank_neg[c,j] = 1 + sum_k sig((s_ck-s_cj)/tau)*pos[c,k]
// out = 61*(w_v/(60+rank_v) + w_l/(60+rank_l))
//
// R22 vs R21 (PASS, 77.7us dispatch, absmax 3.9e-3 = bf16 floor,
// VALUBusy 80%, Occupancy 47%):
//  - inv arrays int -> ushort: LDS 41984 -> ~37.5KB (<=40960) => 4
//    blocks/CU, whole 1024-block grid co-resident (was 3/CU + tail).
//  - DBUK 6 -> 4: margin 0.336 -> 0.202 score. Truncation per excluded
//    elem z^3 = e^{-6.05} = 2.4e-3, total ~0.07 ranks -> <=1.1e-3 output
//    (18x under 2e-2 threshold). Band ~394 -> ~286 elems => hot loop
//    ~68 -> ~49us.
// Predicted dispatch 55-62us.

#define NB 1024
#define CEXP 14.426950408889634f  /* log2(e)/tau, tau=0.1 */
#define SCL  0.000030517578125f   /* 2^-15 */
#define NBUK 128
#define BUK0 4.3f                 /* bucket range [-4.3,4.3] */
#define BUKW 14.883720930f        /* 128/8.6 -> width 0.0672 */
#define DBUK 4                    /* band margin >= 3*0.0672 = 0.202 */
#define CHSZ 128
#define NJOB 32                   /* 8 chunks x 2 matrices x 2 halves */
#define MAXPOS 64
#define ECLMP 1e17f

__device__ __forceinline__ float fma_sat(float a, float b, float c) {
    float d;  // VOP3 clamp [0,1]
    asm("v_fma_f32 %0, %1, %2, %3 clamp" : "=v"(d) : "v"(a), "v"(b), "v"(c));
    return d;
}

__device__ __forceinline__ float nrcp(float d) {
    // d in [2^-120, 1]; magic seed + 2 Newton -> ~1.4e-6 rel (undershoot).
    float r = __uint_as_float(0x7EF311C3u - __float_as_uint(d));
    r = r * fmaf(-d, r, 2.0f);
    r = r * fmaf(-d, r, 2.0f);
    return r;
}

// sum_{i=1..8} 1/y_i, y_i = clamp(Es*R_i + SCL) in [2^-15, 1]
#define TREE(Es, ra, rb, A)                                      \
    {                                                            \
        const float y1 = fma_sat((Es), (ra).x, SCL);             \
        const float y2 = fma_sat((Es), (ra).y, SCL);             \
        const float y3 = fma_sat((Es), (ra).z, SCL);             \
        const float y4 = fma_sat((Es), (ra).w, SCL);             \
        const float y5 = fma_sat((Es), (rb).x, SCL);             \
        const float y6 = fma_sat((Es), (rb).y, SCL);             \
        const float y7 = fma_sat((Es), (rb).z, SCL);             \
        const float y8 = fma_sat((Es), (rb).w, SCL);             \
        const float p12 = y1 * y2, p34 = y3 * y4;                \
        const float p56 = y5 * y6, p78 = y7 * y8;                \
        const float s12 = y1 + y2, s34 = y3 + y4;                \
        const float s56 = y5 + y6, s78 = y7 + y8;                \
        const float q1 = p12 * p34, q2 = p56 * p78;              \
        const float n1 = fmaf(s12, p34, s34 * p12);              \
        const float n2 = fmaf(s56, p78, s78 * p56);              \
        const float num = fmaf(n1, q2, n2 * q1);                 \
        const float den = q1 * q2;                               \
        (A) = fmaf(num, nrcp(den), (A));                         \
    }

__global__ __launch_bounds__(512) void drank_kernel(
    const float* __restrict__ s_v, const float* __restrict__ s_l,
    const unsigned char* __restrict__ pos_m,
    const unsigned char* __restrict__ neg_m,
    const float* __restrict__ w_v, const float* __restrict__ w_l,
    float* __restrict__ out)
{
    __shared__ float  listRv[NB], listRl[NB];     // R, bucket-sorted order
    __shared__ unsigned char bktv[NB], bktl[NB];  // bucket of sorted pos
    __shared__ unsigned short invv[NB], invl[NB]; // orig j -> sorted pos
    __shared__ float  sAv1[NB], sAv2[NB];         // half-band partials
    __shared__ float  sAl1[NB], sAl2[NB];         //   (sorted-pos indexed)
    __shared__ int    offv[NBUK + 1], offl[NBUK + 1];
    __shared__ int    curv[NBUK], curl[NBUK];     // DEDICATED cursors
    __shared__ float  SRv[129], SEv[129];         // octet scans: R-suffix,
    __shared__ float  SR2v[129], SE2v[129];       //   E-prefix, 2nd order
    __shared__ float  SRl[129], SEl[129];
    __shared__ float  SR2l[129], SE2l[129];
    __shared__ float2 posR[MAXPOS];
    __shared__ int    npos_s, jobCtr;

    const int c = blockIdx.x;
    const int t = threadIdx.x;
    const long row = (long)c * NB;

    if (t < NBUK) { curv[t] = 0; curl[t] = 0; }
    if (t == 0) { npos_s = 0; jobCtr = 0; }
    __syncthreads();

    // Mask dtype detect from element (0,0): diagonal -> pos=1, neg=0.
    const unsigned int W =
        ((const unsigned int*)pos_m)[0] ^ ((const unsigned int*)neg_m)[0];
    const int mode = (W == 0x01010101u) ? 0 : ((W == 0x3f800000u) ? 2 : 1);

    // ---- Staging: thread t owns original j/k-pair 2t..2t+1 ----
    const int j0 = t * 2;
    const float2 sjv = *(const float2*)(s_v + row + j0);
    const float2 sjl = *(const float2*)(s_l + row + j0);
    const float svu[2] = {sjv.x, sjv.y};
    const float slu[2] = {sjl.x, sjl.y};

    float Rv[2], Rl[2], Ev[2], El[2];
    int ibv[2], ibl[2];
    #pragma unroll
    for (int u = 0; u < 2; ++u) {
        Rv[u] = __builtin_amdgcn_exp2f(-svu[u] * CEXP);
        Rl[u] = __builtin_amdgcn_exp2f(-slu[u] * CEXP);
        Ev[u] = __builtin_amdgcn_exp2f(svu[u] * CEXP);
        El[u] = __builtin_amdgcn_exp2f(slu[u] * CEXP);
        ibv[u] = max(0, min(NBUK - 1, (int)((svu[u] + BUK0) * BUKW)));
        ibl[u] = max(0, min(NBUK - 1, (int)((slu[u] + BUK0) * BUKW)));
        atomicAdd(&curv[ibv[u]], 1);
        atomicAdd(&curl[ibl[u]], 1);
    }

    bool pj[2];
    if (mode == 0) {
        const unsigned short b = ((const unsigned short*)pos_m)[(row >> 1) + t];
        pj[0] = (b & 0x00ffu) != 0; pj[1] = (b & 0xff00u) != 0;
    } else if (mode == 2) {
        const float2 p = *(const float2*)((const float*)pos_m + row + j0);
        pj[0] = p.x != 0.f; pj[1] = p.y != 0.f;
    } else {
        const int2 p = *(const int2*)((const int*)pos_m + row + j0);
        pj[0] = p.x != 0; pj[1] = p.y != 0;
    }
    #pragma unroll
    for (int u = 0; u < 2; ++u) {
        if (pj[u]) {
            const int idx = atomicAdd(&npos_s, 1);
            if (idx < MAXPOS) posR[idx] = make_float2(Rv[u], Rl[u]);
        }
    }
    __syncthreads();

    // ---- Bucket prefix-sums: wave shuffle-scan (2 waves, 2 buckets/lane);
    //      writes off[] and scatter cursors ----
    if (t < 128) {
        const int m = t >> 6, l = t & 63;
        int* cnt = m ? curl : curv;
        int* off = m ? offl : offv;
        const int c0 = cnt[2 * l], c1 = cnt[2 * l + 1];
        int s = c0 + c1;
        #pragma unroll
        for (int d = 1; d < 64; d <<= 1) {
            const int y = __shfl_up(s, d, 64);
            if (l >= d) s += y;
        }
        const int excl = s - c0 - c1;
        off[2 * l] = excl;     off[2 * l + 1] = excl + c0;
        cnt[2 * l] = excl;     cnt[2 * l + 1] = excl + c0;
        if (l == 63) off[NBUK] = s;
    }
    __syncthreads();

    // ---- Scatter: R + bucket into sorted lists; record inverse perm ----
    #pragma unroll
    for (int u = 0; u < 2; ++u) {
        const int pv = atomicAdd(&curv[ibv[u]], 1);
        listRv[pv] = Rv[u];
        bktv[pv]   = (unsigned char)ibv[u];
        invv[j0 + u] = (unsigned short)pv;
        const int pl = atomicAdd(&curl[ibl[u]], 1);
        listRl[pl] = Rl[u];
        bktl[pl]   = (unsigned char)ibl[u];
        invl[j0 + u] = (unsigned short)pl;
    }
    __syncthreads();

    // ---- Fused octet sums + shuffle scans: 8 waves, one flavor each.
    //      wid: 0 SRv(suf) 1 SEv(pre) 2 SRl(suf) 3 SEl(pre)
    //           4 SR2v(suf) 5 SE2v(pre) 6 SR2l(suf) 7 SE2l(pre)
    //      NOTE: clamp applied ONLY before squaring (1st-order exact) ----
    {
        const int wid = t >> 6, l = t & 63;
        const int m   = (wid >> 1) & 1;   // 0 v, 1 l
        const int fE  = wid & 1;          // E flavor (prefix) vs R (suffix)
        const int sq  = wid >> 2;         // squared
        const float4* L4 = (const float4*)(m ? listRl : listRv);
        float* arr;
        switch (wid) {
            case 0: arr = SRv;  break;  case 1: arr = SEv;  break;
            case 2: arr = SRl;  break;  case 3: arr = SEl;  break;
            case 4: arr = SR2v; break;  case 5: arr = SE2v; break;
            case 6: arr = SR2l; break;  default: arr = SE2l; break;
        }
        const int o0 = fE ? (2 * l) : (127 - 2 * l);
        const int o1 = fE ? (2 * l + 1) : (126 - 2 * l);
        float s01[2];
        #pragma unroll
        for (int q = 0; q < 2; ++q) {
            const int o = q ? o1 : o0;
            const float4 a = L4[2 * o], b = L4[2 * o + 1];
            float x[8] = {a.x, a.y, a.z, a.w, b.x, b.y, b.z, b.w};
            float acc = 0.f;
            #pragma unroll
            for (int i = 0; i < 8; ++i) {
                const float v = fE ? __builtin_amdgcn_rcpf(x[i]) : x[i];
                if (sq) { const float vc = fminf(v, ECLMP); acc += vc * vc; }
                else    { acc += v; }
            }
            s01[q] = acc;
        }
        float s = s01[0] + s01[1];
        #pragma unroll
        for (int d = 1; d < 64; d <<= 1) {
            const float y = __shfl_up(s, d, 64);
            if (l >= d) s += y;
        }
        if (fE) {   // exclusive prefix: arr[o] = sum over octets < o
            const float excl = s - s01[0] - s01[1];
            arr[o0] = excl;  arr[o1] = excl + s01[0];
            if (l == 63) arr[128] = s;
        } else {    // suffix: arr[o] = sum over octets >= o
            arr[o1] = s;  arr[o0] = s - s01[1];
            if (l == 0) arr[128] = 0.f;
        }
    }
    __syncthreads();

    // ---- Banded eval: 32 LPT jobs = 8 chunks x 2 matrices x 2 halves.
    //      Jobs write LANE-OWNED sorted-position slots (no scatter). ----
    static const unsigned char CORD[8] = {3, 4, 2, 5, 1, 6, 0, 7};
    const int lane = t & 63;

    for (;;) {
        int jid0 = 0;
        if (lane == 0) jid0 = atomicAdd(&jobCtr, 1);
        const int jid = __builtin_amdgcn_readfirstlane(jid0);
        if (jid >= NJOB) break;
        const int ch = CORD[jid >> 2];
        const int m  = (jid >> 1) & 1;
        const int h  = jid & 1;

        const float* LR  = m ? listRl : listRv;
        const unsigned char* BK = m ? bktl : bktv;
        const int*   off = m ? offl : offv;
        float*       SA  = h ? (m ? sAl2 : sAv2) : (m ? sAl1 : sAv1);
        const float* SR  = m ? SRl : SRv;
        const float* SE  = m ? SEl : SEv;
        const float* SR2 = m ? SR2l : SR2v;
        const float* SE2 = m ? SE2l : SE2v;
        const float4* L4 = (const float4*)LR;

        const int p0 = ch * CHSZ + 2 * lane;             // sorted positions
        const float2 R2 = *(const float2*)(LR + p0);
        const float Ex = __builtin_amdgcn_rcpf(R2.x);    // E = 1/R
        const float Ey = __builtin_amdgcn_rcpf(R2.y);
        const float EsX = SCL * Ex;
        const float EsY = SCL * Ey;

        const int bs = (int)BK[ch * CHSZ];               // min bucket (sorted)
        const int be = (int)BK[ch * CHSZ + CHSZ - 1];    // max bucket
        const int lo0 = off[max(0, bs - DBUK)] & ~7;
        const int hi0 = (off[min(NBUK - 1, be + DBUK) + 1] + 7) & ~7;
        const int mid = ((lo0 + hi0) >> 1) & ~7;         // octet-aligned
        const int lo = h ? mid : lo0;
        const int hi = h ? hi0 : mid;

        float a0 = 0.f, a1 = 0.f;
        #pragma unroll 2
        for (int p = lo; p < hi; p += 8) {
            const float4 ra = L4[p >> 2];
            const float4 rb = L4[(p >> 2) + 1];
            TREE(EsX, ra, rb, a0);
            TREE(EsY, ra, rb, a1);
        }
        // tail corrections (2nd order):
        //  above (h=1): cnt - E_j*sumR + min(E_j)^2*sum(minR)^2
        //  below (h=0): R_j*sumE - min(R_j)^2*sum(minE)^2
        //  1st-order factors unclamped (products bounded by construction);
        //  clamps only on squared factors (overflow guard).
        float cx, cy;
        if (h) {
            const float sr = SR[hi0 >> 3], sr2 = SR2[hi0 >> 3];
            const float Exc = fminf(Ex, ECLMP), Eyc = fminf(Ey, ECLMP);
            cx = fmaf(Exc * Exc, sr2, (float)(NB - hi0) - Ex * sr);
            cy = fmaf(Eyc * Eyc, sr2, (float)(NB - hi0) - Ey * sr);
        } else {
            const float se = SE[lo0 >> 3], se2 = SE2[lo0 >> 3];
            const float Rxc = fminf(R2.x, ECLMP), Ryc = fminf(R2.y, ECLMP);
            cx = fmaf(-(Rxc * Rxc), se2, R2.x * se);
            cy = fmaf(-(Ryc * Ryc), se2, R2.y * se);
        }
        float2 r;
        r.x = fmaf(a0, SCL, cx);
        r.y = fmaf(a1, SCL, cy);
        *(float2*)(SA + p0) = r;     // lane-owned contiguous write
    }

    // ---- Phase B (before final barrier: overlaps other waves' jobs) ----
    float sPv[2] = {0.f, 0.f};
    float sPl[2] = {0.f, 0.f};
    const int np = min(npos_s, MAXPOS);
    for (int i = 0; i < np; ++i) {
        const float2 rp = posR[i];
        #pragma unroll
        for (int u = 0; u < 2; ++u) {
            sPv[u] += __builtin_amdgcn_rcpf(fmaf(Ev[u], rp.x, 1.0f));
            sPl[u] += __builtin_amdgcn_rcpf(fmaf(El[u], rp.y, 1.0f));
        }
    }
    __syncthreads();

    // ---- Epilogue: gather via inverse permutation, original j order ----
    const int iv0 = invv[j0], iv1 = invv[j0 + 1];
    const int il0 = invl[j0], il1 = invl[j0 + 1];
    const float sAvu[2] = {sAv1[iv0] + sAv2[iv0], sAv1[iv1] + sAv2[iv1]};
    const float sAlu[2] = {sAl1[il0] + sAl2[il0], sAl1[il1] + sAl2[il1]};
    const float2 wv = *(const float2*)(w_v + row + j0);
    const float2 wl = *(const float2*)(w_l + row + j0);
    const float wva[2] = {wv.x, wv.y};
    const float wla[2] = {wl.x, wl.y};
    float o[2];
    #pragma unroll
    for (int u = 0; u < 2; ++u) {
        const float rv = pj[u] ? (1.0f + sAvu[u] - sPv[u]) : (1.0f + sPv[u]);
        const float rl = pj[u] ? (1.0f + sAlu[u] - sPl[u]) : (1.0f + sPl[u]);
        o[u] = 61.0f * (wva[u] / (60.0f + rv) + wla[u] / (60.0f + rl));
    }
    float2 o2;
    o2.x = o[0]; o2.y = o[1];
    *(float2*)(out + row + j0) = o2;
}

extern "C" void kernel_launch(void* const* d_in, const int* in_sizes, int n_in,
                              void* d_out, int out_size, void* d_ws, size_t ws_size,
                              hipStream_t stream) {
    const float* s_v = (const float*)d_in[0];
    const float* s_l = (const float*)d_in[1];
    const unsigned char* pos_m = (const unsigned char*)d_in[2];
    const unsigned char* neg_m = (const unsigned char*)d_in[3];
    const float* w_v = (const float*)d_in[4];
    const float* w_l = (const float*)d_in[5];
    float* out = (float*)d_out;

    drank_kernel<<<dim3(NB), dim3(512), 0, stream>>>(s_v, s_l, pos_m, neg_m, w_v, w_l, out);
}